// Round 1
// baseline (338.211 us; speedup 1.0000x reference)
//
#include <hip/hip_runtime.h>

// Sinkhorn divergence (geomloss 'sinkhorn', p=2, blur=0.05, diameter=4, scaling=0.5, debias)
// B=2, N=M=4096, D=3, fp32.
// R5: wave-uniform chunk skip in the online LSE merge. At small eps the logits span
// thousands of log2 units, so most 64-col chunks sit far below the running row max.
// If ALL lanes' chunk max < running max - 27, the 16 exps contribute < 16*2^-27
// relative to the sum -> skip the exp/accumulate section entirely (saves ~17 exp2
// + ~20 VALU per merge on the transcendental-issue-bound inner loop).
// R4 carried: 16-value merges (4 col-tiles, 8 MFMAs per iter), v_max3 trees,
// packed f32x2 sub/accumulate, MFMA K-slot packing (split-bf16, 3-split T).

typedef __attribute__((ext_vector_type(8))) short short8;
typedef __attribute__((ext_vector_type(8))) __bf16 bf16x8;
typedef __attribute__((ext_vector_type(4))) float f32x4;
typedef __attribute__((ext_vector_type(2))) float f32x2;

#define NPT 4096
#define BLOCK 512
#define COLS 1024           // columns per block (one part)
#define NPARTS 4
#define ROWS_PER_BLOCK 256  // 8 waves x 2 rowsets x 16
#define NRC 16              // rowchunks
#define EXP2 __builtin_amdgcn_exp2f
#define LOG2 __builtin_amdgcn_logf
#define KLOG2E 1.4426950408889634f
#define KLN2 0.6931471805599453f
#define SKIP_THR 27.0f      // log2-units below running max where a chunk is dropped

__device__ inline unsigned short f2bf(float f) {
  unsigned u = __float_as_uint(f);
  return (unsigned short)((u + 0x7FFF + ((u >> 16) & 1)) >> 16);
}
__device__ inline float bf2f(unsigned short h) {
  return __uint_as_float(((unsigned)h) << 16);
}

struct SArgs {
  const float* rowPts[4];
  const float* colPts[4];
  const float2* Pprev;   // partials from previous launch [8 tbl][4 part][4096] (m,s)
  float2* Pcur;
  const float* Fprev;    // finalized potentials [8 tbl][4096]
  float* Fcur;
  float eps, epsPrev;
  int usePot, avgPrev;
};

// merge 16 values into running (m,s); max3-friendly tree + packed f32x2 sub/sum.
// Wave-uniform early-out when the whole chunk is numerically irrelevant.
__device__ inline void lse_merge16(float& m, float& s,
                                   f32x4 c0, f32x4 c1, f32x4 c2, f32x4 c3) {
  float t0 = fmaxf(fmaxf(c0.x, c0.y), c0.z);
  float t1 = fmaxf(fmaxf(c0.w, c1.x), c1.y);
  float t2 = fmaxf(fmaxf(c1.z, c1.w), c2.x);
  float t3 = fmaxf(fmaxf(c2.y, c2.z), c2.w);
  float t4 = fmaxf(fmaxf(c3.x, c3.y), c3.z);
  float u0 = fmaxf(fmaxf(t0, t1), c3.w);
  float u1 = fmaxf(fmaxf(t2, t3), t4);
  float cm = fmaxf(u0, u1);
  // chunk contributes < 16*2^-27 relative for every lane -> drop it.
  // m = -inf on the first merge makes the predicate false (cm finite), so the
  // first chunk always runs the full path.
  if (__all(cm < m - SKIP_THR)) return;
  float mn = fmaxf(m, cm);
  float sc = EXP2(m - mn);                 // m=-inf first iter -> 0
  f32x2 mn2 = {mn, mn};
  f32x2 sa = {0.0f, 0.0f}, sb = {0.0f, 0.0f};
  f32x2 d;
  d = (f32x2){c0.x, c0.y} - mn2; sa += (f32x2){EXP2(d.x), EXP2(d.y)};
  d = (f32x2){c0.z, c0.w} - mn2; sb += (f32x2){EXP2(d.x), EXP2(d.y)};
  d = (f32x2){c1.x, c1.y} - mn2; sa += (f32x2){EXP2(d.x), EXP2(d.y)};
  d = (f32x2){c1.z, c1.w} - mn2; sb += (f32x2){EXP2(d.x), EXP2(d.y)};
  d = (f32x2){c2.x, c2.y} - mn2; sa += (f32x2){EXP2(d.x), EXP2(d.y)};
  d = (f32x2){c2.z, c2.w} - mn2; sb += (f32x2){EXP2(d.x), EXP2(d.y)};
  d = (f32x2){c3.x, c3.y} - mn2; sa += (f32x2){EXP2(d.x), EXP2(d.y)};
  d = (f32x2){c3.z, c3.w} - mn2; sb += (f32x2){EXP2(d.x), EXP2(d.y)};
  sa += sb;
  s = fmaf(s, sc, sa.x + sa.y);
  m = mn;
}

__global__ __launch_bounds__(BLOCK, 4) void softmin_mfma(SArgs A) {
  __shared__ short8 fragA0[COLS];   // k0..7  per column
  __shared__ short8 fragA1[COLS];   // k8..15 per column

  const int bid  = blockIdx.x;
  const int tbl  = bid >> 6;          // 0..7 = task*2+batch
  const int task = tbl >> 1, batch = tbl & 1;
  const int rem  = bid & 63;
  const int part = rem >> 4;
  const int rc   = rem & 15;

  const float* yp = A.colPts[task] + batch * NPT * 3;
  const float* xp = A.rowPts[task] + batch * NPT * 3;

  const float inv_eps = 1.0f / A.eps;
  const float sY = inv_eps * KLOG2E;
  const float hc = -8.317766166719343f;   // -ln(4096)
  const int pidxA[4] = {1, 0, 2, 3};
  const int tP = pidxA[task] * 2 + batch;

  const int lane = threadIdx.x & 63;
  const int wave = threadIdx.x >> 6;
  const int q    = lane >> 4;

  // ---- build B fragments (row side), 2 rowsets of 16 rows per wave ----
  const int rowbase = rc * ROWS_PER_BLOCK + wave * 32;
  bf16x8 Bf[2];
#pragma unroll
  for (int rs = 0; rs < 2; ++rs) {
    int i = rowbase + rs * 16 + (lane & 15);
    float X0 = xp[3 * i], X1 = xp[3 * i + 1], X2 = xp[3 * i + 2];
    unsigned short xh0 = f2bf(X0), xh1 = f2bf(X1), xh2 = f2bf(X2);
    unsigned short xl0 = f2bf(X0 - bf2f(xh0));
    unsigned short xl1 = f2bf(X1 - bf2f(xh1));
    unsigned short xl2 = f2bf(X2 - bf2f(xh2));
    short8 bb = (short8)0;
    if (q == 0) {
      short8 t = {(short)xh0, (short)xh1, (short)xh2,
                  (short)xh0, (short)xh1, (short)xh2,
                  (short)xl0, (short)xl1};
      bb = t;
    } else if (q == 1) {
      short8 t = {(short)xl2, (short)0x3F80, (short)0x3F80, (short)0x3F80,
                  (short)xl0, (short)xl1, (short)xl2, 0};
      bb = t;
    }
    Bf[rs] = __builtin_bit_cast(bf16x8, bb);
  }

  // ---- staging: finalize prev-launch potentials + build column A-fragments ----
  for (int c = 0; c < COLS / BLOCK; ++c) {
    int jl = threadIdx.x + c * BLOCK;
    int j  = part * COLS + jl;
    float y0 = yp[3 * j], y1 = yp[3 * j + 1], y2 = yp[3 * j + 2];
    float y2n = 0.5f * (y0 * y0 + y1 * y1 + y2 * y2);
    float pot = 0.0f;
    if (A.usePot) {
      float2 q0 = A.Pprev[(tP * 4 + 0) * NPT + j];
      float2 q1 = A.Pprev[(tP * 4 + 1) * NPT + j];
      float2 q2 = A.Pprev[(tP * 4 + 2) * NPT + j];
      float2 q3 = A.Pprev[(tP * 4 + 3) * NPT + j];
      float M = fmaxf(fmaxf(q0.x, q1.x), fmaxf(q2.x, q3.x));
      float S = q0.y * EXP2(q0.x - M) + q1.y * EXP2(q1.x - M)
              + q2.y * EXP2(q2.x - M) + q3.y * EXP2(q3.x - M);
      float L = M + LOG2(S);
      float r = y2n - A.epsPrev * KLN2 * L;
      if (A.avgPrev) r = 0.5f * (A.Fprev[tP * NPT + j] + r);
      pot = r;
      if (rc == 0) A.Fcur[tP * NPT + j] = pot;
    }
    float T = (hc + (pot - y2n) * inv_eps) * KLOG2E;
    float s0 = y0 * sY, s1 = y1 * sY, s2 = y2 * sY;
    unsigned short yh0 = f2bf(s0), yh1 = f2bf(s1), yh2 = f2bf(s2);
    unsigned short yl0 = f2bf(s0 - bf2f(yh0));
    unsigned short yl1 = f2bf(s1 - bf2f(yh1));
    unsigned short yl2 = f2bf(s2 - bf2f(yh2));
    unsigned short Th = f2bf(T);
    float tr = T - bf2f(Th);
    unsigned short Tm = f2bf(tr);
    tr -= bf2f(Tm);
    unsigned short Tl = f2bf(tr);
    short8 h0 = {(short)yh0, (short)yh1, (short)yh2,
                 (short)yl0, (short)yl1, (short)yl2,
                 (short)yh0, (short)yh1};
    short8 h1 = {(short)yh2, (short)Th, (short)Tm, (short)Tl,
                 (short)yl0, (short)yl1, (short)yl2, 0};
    fragA0[jl] = h0;
    fragA1[jl] = h1;
  }
  __syncthreads();

  // ---- inner loop: 4 column tiles (64 cols) per iteration, 8 MFMAs ----
  const short8* srcA = (lane & 16) ? fragA1 : fragA0;
  const int colsel = lane & 15;
  const f32x4 Z = {0.0f, 0.0f, 0.0f, 0.0f};
  short8 as0 = (short8)0, as1 = (short8)0, as2 = (short8)0, as3 = (short8)0;
  float m0 = -__builtin_inff(), s0_ = 0.0f;
  float m1 = -__builtin_inff(), s1_ = 0.0f;

  for (int jt = 0; jt < COLS / 16; jt += 4) {
    if (lane < 32) {
      as0 = srcA[(jt + 0) * 16 + colsel];
      as1 = srcA[(jt + 1) * 16 + colsel];
      as2 = srcA[(jt + 2) * 16 + colsel];
      as3 = srcA[(jt + 3) * 16 + colsel];
    }
    bf16x8 A0 = __builtin_bit_cast(bf16x8, as0);
    bf16x8 A1 = __builtin_bit_cast(bf16x8, as1);
    bf16x8 A2 = __builtin_bit_cast(bf16x8, as2);
    bf16x8 A3 = __builtin_bit_cast(bf16x8, as3);
    f32x4 c00 = __builtin_amdgcn_mfma_f32_16x16x32_bf16(A0, Bf[0], Z, 0, 0, 0);
    f32x4 c01 = __builtin_amdgcn_mfma_f32_16x16x32_bf16(A1, Bf[0], Z, 0, 0, 0);
    f32x4 c02 = __builtin_amdgcn_mfma_f32_16x16x32_bf16(A2, Bf[0], Z, 0, 0, 0);
    f32x4 c03 = __builtin_amdgcn_mfma_f32_16x16x32_bf16(A3, Bf[0], Z, 0, 0, 0);
    f32x4 c10 = __builtin_amdgcn_mfma_f32_16x16x32_bf16(A0, Bf[1], Z, 0, 0, 0);
    f32x4 c11 = __builtin_amdgcn_mfma_f32_16x16x32_bf16(A1, Bf[1], Z, 0, 0, 0);
    f32x4 c12 = __builtin_amdgcn_mfma_f32_16x16x32_bf16(A2, Bf[1], Z, 0, 0, 0);
    f32x4 c13 = __builtin_amdgcn_mfma_f32_16x16x32_bf16(A3, Bf[1], Z, 0, 0, 0);
    lse_merge16(m0, s0_, c00, c01, c02, c03);
    lse_merge16(m1, s1_, c10, c11, c12, c13);
  }

  // ---- cross-quad merge (lanes sharing same row i: xor 16, xor 32) + store partial ----
#pragma unroll
  for (int rs = 0; rs < 2; ++rs) {
    float m = rs ? m1 : m0;
    float s = rs ? s1_ : s0_;
#pragma unroll
    for (int off = 16; off <= 32; off <<= 1) {
      float mo = __shfl_xor(m, off, 64);
      float so = __shfl_xor(s, off, 64);
      float mn = fmaxf(m, mo);
      s = s * EXP2(m - mn) + so * EXP2(mo - mn);
      m = mn;
    }
    if (lane < 16) {
      int i = rowbase + rs * 16 + lane;
      A.Pcur[(tbl * 4 + part) * NPT + i] = make_float2(m, s);
    }
  }
}

// reduce1: finalize last-launch partials, per-row contribution, per-block partial sums
__global__ __launch_bounds__(256) void reduce1(const float2* P, float* R1) {
  int u = blockIdx.x * 256 + threadIdx.x;   // 0..8191
  int b = u >> 12, i = u & 4095;
  float Ls[4];
#pragma unroll
  for (int t = 0; t < 4; ++t) {
    int tbl = t * 2 + b;
    float2 q0 = P[(tbl * 4 + 0) * NPT + i];
    float2 q1 = P[(tbl * 4 + 1) * NPT + i];
    float2 q2 = P[(tbl * 4 + 2) * NPT + i];
    float2 q3 = P[(tbl * 4 + 3) * NPT + i];
    float M = fmaxf(fmaxf(q0.x, q1.x), fmaxf(q2.x, q3.x));
    float S = q0.y * EXP2(q0.x - M) + q1.y * EXP2(q1.x - M)
            + q2.y * EXP2(q2.x - M) + q3.y * EXP2(q3.x - M);
    Ls[t] = M + LOG2(S);
  }
  // (b_x - a_x) + (a_y - b_y) = -eps*ln2*((L0 - L2) + (L1 - L3))
  float acc = (Ls[0] - Ls[2]) + (Ls[1] - Ls[3]);
#pragma unroll
  for (int off = 32; off >= 1; off >>= 1) acc += __shfl_xor(acc, off, 64);
  __shared__ float red[4];
  int wave = threadIdx.x >> 6, lane = threadIdx.x & 63;
  if (lane == 0) red[wave] = acc;
  __syncthreads();
  if (threadIdx.x == 0)
    R1[blockIdx.x] = red[0] + red[1] + red[2] + red[3];
}

__global__ __launch_bounds__(64) void reduce2(const float* R1, float* out) {
  float a = (threadIdx.x < 32) ? R1[threadIdx.x] : 0.0f;
#pragma unroll
  for (int off = 32; off >= 1; off >>= 1) a += __shfl_xor(a, off, 64);
  if (threadIdx.x == 0)
    out[0] = a * (-0.0025f * KLN2 / 4096.0f);
}

extern "C" void kernel_launch(void* const* d_in, const int* in_sizes, int n_in,
                              void* d_out, int out_size, void* d_ws, size_t ws_size,
                              hipStream_t stream) {
  const float* x = (const float*)d_in[0];   // true_data
  const float* y = (const float*)d_in[1];   // particles
  float* out = (float*)d_out;
  float* W = (float*)d_ws;

  float2* P[2] = { (float2*)W, (float2*)(W + 262144) };     // 2 x 1 MB partials
  float*  F[2] = { W + 524288, W + 557056 };                // 2 x 128 KB finalized pots
  float*  R1buf = W + 589824;                               // 32 floats

  // launch schedule: L0 init; L1..9 loop (eps_list); L10 final extrapolation
  static const float epsL[11] = {16.0f, 16.0f, 16.0f, 4.0f, 1.0f, 0.25f, 0.0625f,
                                 0.015625f, 0.00390625f, 0.0025f, 0.0025f};
  static const int avgL[11] = {0, 1, 1, 1, 1, 1, 1, 1, 1, 1, 0};

  const float* rows[4] = { x, y, x, y };   // b_x<-C_xy, a_y<-C_yx, a_x<-C_xx, b_y<-C_yy
  const float* cols[4] = { y, x, x, y };

  dim3 grid(8 * NPARTS * NRC), block(BLOCK);
  for (int L = 0; L <= 10; ++L) {
    SArgs A;
    for (int t = 0; t < 4; ++t) { A.rowPts[t] = rows[t]; A.colPts[t] = cols[t]; }
    A.Pprev = P[(L + 1) & 1];
    A.Pcur  = P[L & 1];
    A.Fprev = F[(L + 1) & 1];
    A.Fcur  = F[L & 1];
    A.eps = epsL[L];
    A.epsPrev = (L > 0) ? epsL[L - 1] : 1.0f;
    A.usePot = (L > 0) ? 1 : 0;
    A.avgPrev = (L > 0) ? avgL[L - 1] : 0;
    softmin_mfma<<<grid, block, 0, stream>>>(A);
  }
  reduce1<<<32, 256, 0, stream>>>(P[0], R1buf);   // L=10 wrote P[10&1]=P[0]
  reduce2<<<1, 64, 0, stream>>>(R1buf, out);
}